// Round 6
// baseline (487.751 us; speedup 1.0000x reference)
//
#include <hip/hip_runtime.h>
#include <cmath>

#define B_ 4
#define T_ 8192
#define C_ 256
#define E_ 8
#define M_ (B_*T_)
#define NCH 64

typedef __bf16 bf16x8 __attribute__((ext_vector_type(8)));
typedef float  f32x16 __attribute__((ext_vector_type(16)));

typedef const __attribute__((address_space(1))) unsigned int* gas_t;
typedef __attribute__((address_space(3))) unsigned int* las_t;

static __device__ __forceinline__ unsigned short f2bf(float f) {
    union { float fv; unsigned u; } v; v.fv = f;
    unsigned r = v.u + 0x7FFFu + ((v.u >> 16) & 1u);
    return (unsigned short)(r >> 16);
}

// Abramowitz-Stegun 7.1.26: |err| <= 1.5e-7
static __device__ __forceinline__ float fast_erf(float x) {
    float ax = fabsf(x);
    float t = __builtin_amdgcn_rcpf(1.0f + 0.3275911f * ax);
    float p = ((((1.061405429f * t - 1.453152027f) * t) + 1.421413741f) * t - 0.284496736f) * t + 0.254829592f;
    float y = 1.0f - p * t * __expf(-ax * ax);
    return copysignf(y, x);
}

static __device__ __forceinline__ float gelu_f(float x) {
    return 0.5f * x * (1.0f + fast_erf(x * 0.7071067811865476f));
}

static __device__ __forceinline__ f32x16 mfma32(bf16x8 a, bf16x8 b, f32x16 c) {
    return __builtin_amdgcn_mfma_f32_32x32x16_bf16(a, b, c, 0, 0, 0);
}

// stage one 32KB chunk [256 cols][64 k] bf16 into LDS (512 threads, 4 x 16B each).
// LDS 16B-slot s holds (col = s>>3, kseg = (s&7) ^ (col&7)) -> read-side XOR matches.
// chunk c: expert c>>3; (c&7)<4 -> w1t slab (c&3), else w2t slab (c&3).
static __device__ __forceinline__ void stage_chunk(const unsigned short* __restrict__ w1t,
                                                   const unsigned short* __restrict__ w2t,
                                                   int c, unsigned short* lds, int tid) {
    int gq = c & 7;
    const unsigned short* src = ((gq & 4) ? w2t : w1t) + ((c >> 3) << 16) + ((gq & 3) << 6);
#pragma unroll
    for (int j = 0; j < 4; j++) {
        int s = (j << 9) + tid;
        int col = s >> 3;
        int kseg = (s & 7) ^ (col & 7);
        const unsigned short* gp = src + (col << 8) + (kseg << 3);
        unsigned short* lp = lds + (((j << 9) + (tid & ~63)) << 3);
        __builtin_amdgcn_global_load_lds((gas_t)(const void*)gp, (las_t)(void*)lp, 16, 0, 0);
    }
}

// ---------------- prep kernels ----------------

// w1t[e][c][k] = W1[e][k][c], k in [0,256)  (tiled coalesced transpose)
__global__ void k_w1t(const float* __restrict__ W1, unsigned short* __restrict__ w1t) {
    __shared__ float tile[64][65];
    int e = blockIdx.x >> 4, kt = (blockIdx.x >> 2) & 3, ct = blockIdx.x & 3;
    int k0 = kt << 6, c0 = ct << 6;
    const float* src = W1 + ((size_t)e << 18) + ((size_t)k0 << 8) + c0;
    int r = threadIdx.x >> 6, col = threadIdx.x & 63;
#pragma unroll
    for (int i = 0; i < 16; i++)
        tile[r + i * 4][col] = src[(size_t)(r + i * 4) * 256 + col];
    __syncthreads();
    unsigned short* dst = w1t + (e << 16) + (c0 << 8) + k0;
#pragma unroll
    for (int i = 0; i < 16; i++)
        dst[(r + i * 4) * 256 + col] = f2bf(tile[col][r + i * 4]);
}

// w2t[e][f][c] = W2[e][c][f]
__global__ void k_w2t(const float* __restrict__ W2, unsigned short* __restrict__ w2t) {
    __shared__ float tile[64][65];
    int e = blockIdx.x >> 4, ct = (blockIdx.x >> 2) & 3, ft = blockIdx.x & 3;
    int c0 = ct << 6, f0 = ft << 6;
    const float* src = W2 + ((size_t)e << 16) + ((size_t)c0 << 8) + f0;
    int r = threadIdx.x >> 6, col = threadIdx.x & 63;
#pragma unroll
    for (int i = 0; i < 16; i++)
        tile[r + i * 4][col] = src[(size_t)(r + i * 4) * 256 + col];
    __syncthreads();
    unsigned short* dst = w2t + (e << 16) + (f0 << 8) + c0;
#pragma unroll
    for (int i = 0; i < 16; i++)
        dst[(r + i * 4) * 256 + col] = f2bf(tile[col][r + i * 4]);
}

// v2[e][c] = sum_f W2[e,c,f]*We[e,f];  c2[e] = sum_f b2[e,f]*We[e,f] + be[e]
__global__ void k_v2(const float* __restrict__ W2, const float* __restrict__ We,
                     const float* __restrict__ b2, const float* __restrict__ be,
                     float* __restrict__ v2, float* __restrict__ c2) {
    __shared__ float sm[4];
    int e = blockIdx.x >> 8, c = blockIdx.x & 255, f = threadIdx.x;
    float wef = We[(e << 8) + f];
    float v = W2[((((e << 8) + c) << 8)) + f] * wef;
#pragma unroll
    for (int m = 32; m >= 1; m >>= 1) v += __shfl_xor(v, m);
    if ((f & 63) == 0) sm[f >> 6] = v;
    __syncthreads();
    if (f == 0) v2[(e << 8) + c] = sm[0] + sm[1] + sm[2] + sm[3];
    if (c == 0) {
        __syncthreads();
        float u = b2[(e << 8) + f] * wef;
#pragma unroll
        for (int m = 32; m >= 1; m >>= 1) u += __shfl_xor(u, m);
        if ((f & 63) == 0) sm[f >> 6] = u;
        __syncthreads();
        if (f == 0) c2[e] = sm[0] + sm[1] + sm[2] + sm[3] + be[e];
    }
}

// ---------------- LN + masked stats (+ x -> bf16 conversion fused) ----------------

__global__ void k_stats(const float* __restrict__ x, const int* __restrict__ mask,
                        const float* __restrict__ lnw, const float* __restrict__ lnb,
                        float* __restrict__ S1, float* __restrict__ S2, float* __restrict__ ncnt,
                        unsigned short* __restrict__ xb) {
    int b = blockIdx.x >> 6;
    int chunk = blockIdx.x & 63;
    int wid = threadIdx.x >> 6, lane = threadIdx.x & 63;
    int c0 = lane << 2;
    float4 w4 = *reinterpret_cast<const float4*>(lnw + c0);
    float4 b4 = *reinterpret_cast<const float4*>(lnb + c0);
    float a1[4] = {0,0,0,0}, a2[4] = {0,0,0,0};
    int cnt = 0;
    int tbase = chunk * 128;
    for (int r = wid; r < 128; r += 4) {
        int row = b * T_ + tbase + r;
        float4 xv = *reinterpret_cast<const float4*>(x + (size_t)row * C_ + c0);
        ushort4 o;
        o.x = f2bf(xv.x); o.y = f2bf(xv.y); o.z = f2bf(xv.z); o.w = f2bf(xv.w);
        *reinterpret_cast<ushort4*>(xb + (size_t)row * C_ + c0) = o;
        float s1 = xv.x + xv.y + xv.z + xv.w;
        float s2 = xv.x*xv.x + xv.y*xv.y + xv.z*xv.z + xv.w*xv.w;
#pragma unroll
        for (int m = 1; m < 64; m <<= 1) { s1 += __shfl_xor(s1, m); s2 += __shfl_xor(s2, m); }
        if (mask[row]) {
            float mu = s1 * (1.f / C_);
            float var = s2 * (1.f / C_) - mu * mu;
            float rs = rsqrtf(var + 1e-5f);
            float hv;
            hv = (xv.x - mu) * rs * w4.x + b4.x; a1[0] += hv; a2[0] += hv * hv;
            hv = (xv.y - mu) * rs * w4.y + b4.y; a1[1] += hv; a2[1] += hv * hv;
            hv = (xv.z - mu) * rs * w4.z + b4.z; a1[2] += hv; a2[2] += hv * hv;
            hv = (xv.w - mu) * rs * w4.w + b4.w; a1[3] += hv; a2[3] += hv * hv;
            cnt++;
        }
    }
    __shared__ float red[4][256];
    __shared__ int rc[4];
#pragma unroll
    for (int j = 0; j < 4; j++) red[wid][c0 + j] = a1[j];
    if (lane == 0) rc[wid] = cnt;
    __syncthreads();
    int ch = threadIdx.x;
    float s = red[0][ch] + red[1][ch] + red[2][ch] + red[3][ch];
    atomicAdd(&S1[(b << 8) + ch], s);
    if (threadIdx.x == 0) atomicAdd(&ncnt[b], (float)(rc[0] + rc[1] + rc[2] + rc[3]));
    __syncthreads();
#pragma unroll
    for (int j = 0; j < 4; j++) red[wid][c0 + j] = a2[j];
    __syncthreads();
    s = red[0][ch] + red[1][ch] + red[2][ch] + red[3][ch];
    atomicAdd(&S2[(b << 8) + ch], s);
}

__global__ void k_stats_fin(const float* __restrict__ S1, const float* __restrict__ S2,
                            const float* __restrict__ ncnt, float* __restrict__ stats) {
    int b = blockIdx.x, c = threadIdx.x;
    float n = fmaxf(ncnt[b], 1.f);
    float mean = S1[(b << 8) + c] / n;
    float var_b = fmaxf(S2[(b << 8) + c] / n - mean * mean, 0.f);
    float var_u = (n > 1.f) ? (var_b * (n / fmaxf(n - 1.f, 1e-9f))) : var_b;
    float std_u = fmaxf(sqrtf(var_u), 1e-9f);
    stats[b * 768 + 0 * 256 + c] = mean;
    stats[b * 768 + 1 * 256 + c] = std_u;
    stats[b * 768 + 2 * 256 + c] = var_u;
}

__global__ void k_bias(const float* __restrict__ W1, const float* __restrict__ b1,
                       const float* __restrict__ stats, float* __restrict__ bias) {
    int b = blockIdx.x >> 3, e = blockIdx.x & 7, c = threadIdx.x;
    __shared__ float sm[768];
    for (int i = threadIdx.x; i < 768; i += 256) sm[i] = stats[b * 768 + i];
    __syncthreads();
    const float* w = W1 + (size_t)e * 1024 * 256;
    float acc = b1[(e << 8) + c];
#pragma unroll 4
    for (int j = 0; j < 256; j++) {
        acc += sm[j]       * w[(256 + j) * 256 + c];
        acc += sm[256 + j] * w[(512 + j) * 256 + c];
        acc += sm[512 + j] * w[(768 + j) * 256 + c];
    }
    bias[((b << 3) + e) * 256 + c] = acc;
}

// ---------------- fused: GEMM1 + gelu + energies + online softmax + GEMM2 ----------------
// 256 blocks x 512 threads, 128 rows/block. 8 waves: mw=w>>2 (64-row half),
// nw=w&3 (64-col quarter). 32x32x16 MFMA. Counted-vmcnt pipeline: raw s_barrier +
// s_waitcnt vmcnt(4) keeps the next 32KB chunk's 4 loads/thread in flight across
// barriers (never drains to 0 in the loop). All scalar/global preloads are issued
// BEFORE the stage-issue so FIFO vmcnt(4) retires them.

__global__ __launch_bounds__(512, 2) void k_fused(
    const unsigned short* __restrict__ xb, const unsigned short* __restrict__ w1t,
    const unsigned short* __restrict__ w2t, const float* __restrict__ bias,
    const float* __restrict__ v2, const float* __restrict__ c2,
    const int* __restrict__ mask, const float* __restrict__ b2,
    const float* __restrict__ log_beta, const float* __restrict__ prior,
    float* __restrict__ out) {
    __shared__ unsigned short stg[2][16384];  // 2 x 32KB weight chunks (swizzled)
    __shared__ unsigned short h1s[32768];     // [128][256] bf16, row-swizzled
    __shared__ float nbs[128][8];
    __shared__ float scr[512];                // enp[4][128]; reused as sinv[128] at end
    __shared__ float rs_[128], us_[128];

    int row0 = blockIdx.x << 7;
    int b = row0 >> 13;
    int tid = threadIdx.x;
    int w = tid >> 6, lane = tid & 63;
    int mw = w >> 2, nw = w & 3;
    int nwo = nw << 6;
    int c_ = lane & 31, hi = lane >> 5;

    int mreg = 0; float m_run = -3.0e38f; float beta = 0.f;
    if (tid < 128) { mreg = mask[row0 + tid]; beta = __expf(log_beta[0]); }

    const unsigned short* arow0 = xb + (size_t)(row0 + (mw << 6) + c_) * C_ + (hi << 3);
    int rowA0 = (mw << 6) + c_;

    f32x16 acc2[2][2], accG[2][2];
#pragma unroll
    for (int mt = 0; mt < 2; mt++)
#pragma unroll
        for (int nt = 0; nt < 2; nt++)
#pragma unroll
            for (int r = 0; r < 16; r++) acc2[mt][nt][r] = 0.f;

    stage_chunk(w1t, w2t, 0, stg[0], tid);

    for (int e = 0; e < E_; e++) {
        const float* bre = bias + (((b << 3) + e) << 8);
        float v2v[2];
        // ================= GEMM1: 4 phases (chunks e*8+g) =================
#pragma unroll
        for (int g = 0; g < 4; g++) {
            int p = (e << 3) + g;
            // ---- phase-top preloads (older than the stage issue below) ----
            bf16x8 a[2][4];
#pragma unroll
            for (int mt = 0; mt < 2; mt++)
#pragma unroll
                for (int kf = 0; kf < 4; kf++)
                    a[mt][kf] = *reinterpret_cast<const bf16x8*>(arow0 + (mt << 13) + (g << 6) + (kf << 4));
            float bv[2];
            if (g == 0) {
#pragma unroll
                for (int nt = 0; nt < 2; nt++) bv[nt] = bre[nwo + (nt << 5) + c_];
            }
            if (g == 3) {
#pragma unroll
                for (int nt = 0; nt < 2; nt++) v2v[nt] = v2[(e << 8) + nwo + (nt << 5) + c_];
            }
            asm volatile("" ::: "memory");
            // ---- stage next chunk + counted wait + barrier ----
            int nc = p + 1;
            if (nc < NCH) {
                stage_chunk(w1t, w2t, nc, stg[nc & 1], tid);
                asm volatile("s_waitcnt vmcnt(4) lgkmcnt(0)" ::: "memory");
            } else {
                asm volatile("s_waitcnt vmcnt(0) lgkmcnt(0)" ::: "memory");
            }
            __builtin_amdgcn_s_barrier();
            if (g == 0) {
#pragma unroll
                for (int mt = 0; mt < 2; mt++)
#pragma unroll
                    for (int nt = 0; nt < 2; nt++)
#pragma unroll
                        for (int r = 0; r < 16; r++) accG[mt][nt][r] = bv[nt];
            }
            const unsigned short* bs = stg[g & 1];
            __builtin_amdgcn_s_setprio(1);
#pragma unroll
            for (int kf = 0; kf < 4; kf++) {
                bf16x8 bq[2];
#pragma unroll
                for (int nt = 0; nt < 2; nt++) {
                    int col = nwo + (nt << 5) + c_;
                    int kseg = (kf << 1) + hi;
                    int slot = (col << 3) + (kseg ^ (col & 7));
                    bq[nt] = *reinterpret_cast<const bf16x8*>(bs + (slot << 3));
                }
#pragma unroll
                for (int mt = 0; mt < 2; mt++)
#pragma unroll
                    for (int nt = 0; nt < 2; nt++)
                        accG[mt][nt] = mfma32(a[mt][kf], bq[nt], accG[mt][nt]);
            }
            __builtin_amdgcn_s_setprio(0);
            if (g == 3) {
                // ---- tail: gelu + energy partials + h1 -> LDS ----
                float epr[2][16];
#pragma unroll
                for (int mt = 0; mt < 2; mt++)
#pragma unroll
                    for (int r = 0; r < 16; r++) {
                        float s = 0.f;
#pragma unroll
                        for (int nt = 0; nt < 2; nt++) {
                            float gl = gelu_f(accG[mt][nt][r]);
                            accG[mt][nt][r] = gl;
                            s += gl * v2v[nt];
                        }
                        epr[mt][r] = s;
                    }
#pragma unroll
                for (int m = 1; m < 32; m <<= 1)
#pragma unroll
                    for (int mt = 0; mt < 2; mt++)
#pragma unroll
                        for (int r = 0; r < 16; r++) epr[mt][r] += __shfl_xor(epr[mt][r], m);
#pragma unroll
                for (int mt = 0; mt < 2; mt++)
#pragma unroll
                    for (int r = 0; r < 16; r++) {
                        int rowl = (mw << 6) + (mt << 5) + (r & 3) + ((r >> 2) << 3) + (hi << 2);
#pragma unroll
                        for (int nt = 0; nt < 2; nt++) {
                            int col = nwo + (nt << 5) + c_;
                            int byteoff = ((rowl << 9) + (col << 1)) ^ ((rowl & 7) << 4);
                            *reinterpret_cast<unsigned short*>(reinterpret_cast<char*>(h1s) + byteoff)
                                = f2bf(accG[mt][nt][r]);
                        }
                        if (c_ == 0) scr[(nw << 7) + rowl] = epr[mt][r];
                    }
            }
            asm volatile("s_waitcnt lgkmcnt(0)" ::: "memory");
            __builtin_amdgcn_s_barrier();
        }
        // ================= GEMM2: 4 phases (chunks e*8+4+g) =================
#pragma unroll
        for (int g = 0; g < 4; g++) {
            int p = (e << 3) + 4 + g;
            float b2v[2];
            if (g == 0) {
                // online softmax update (row = tid; enp visible after prev barrier)
                if (tid < 128) {
                    float en = scr[tid] + scr[128 + tid] + scr[256 + tid] + scr[384 + tid] + c2[e];
                    float nb = -beta * (en + prior[e]);
                    nbs[tid][e] = nb;
                    float mn = fmaxf(m_run, nb);
                    rs_[tid] = __expf(m_run - mn);
                    us_[tid] = __expf(nb - mn);
                    m_run = mn;
                }
#pragma unroll
                for (int nt = 0; nt < 2; nt++) b2v[nt] = b2[(e << 8) + nwo + (nt << 5) + c_];
            }
            asm volatile("" ::: "memory");
            int nc = p + 1;
            if (nc < NCH) {
                stage_chunk(w1t, w2t, nc, stg[nc & 1], tid);
                asm volatile("s_waitcnt vmcnt(4) lgkmcnt(0)" ::: "memory");
            } else {
                asm volatile("s_waitcnt vmcnt(0) lgkmcnt(0)" ::: "memory");
            }
            __builtin_amdgcn_s_barrier();
            if (g == 0) {
#pragma unroll
                for (int mt = 0; mt < 2; mt++)
#pragma unroll
                    for (int nt = 0; nt < 2; nt++)
#pragma unroll
                        for (int r = 0; r < 16; r++) accG[mt][nt][r] = b2v[nt];
            }
            const unsigned short* bs = stg[g & 1];
            // A-fragments from swizzled h1s
            bf16x8 a[2][4];
#pragma unroll
            for (int mt = 0; mt < 2; mt++) {
                int rowA = rowA0 + (mt << 5);
                int rswz = (rowA & 7) << 4;
#pragma unroll
                for (int kf = 0; kf < 4; kf++) {
                    int byteoff = ((rowA << 9) + (g << 7) + (kf << 5) + (hi << 4)) ^ rswz;
                    a[mt][kf] = *reinterpret_cast<const bf16x8*>(reinterpret_cast<const char*>(h1s) + byteoff);
                }
            }
            __builtin_amdgcn_s_setprio(1);
#pragma unroll
            for (int kf = 0; kf < 4; kf++) {
                bf16x8 bq[2];
#pragma unroll
                for (int nt = 0; nt < 2; nt++) {
                    int col = nwo + (nt << 5) + c_;
                    int kseg = (kf << 1) + hi;
                    int slot = (col << 3) + (kseg ^ (col & 7));
                    bq[nt] = *reinterpret_cast<const bf16x8*>(bs + (slot << 3));
                }
#pragma unroll
                for (int mt = 0; mt < 2; mt++)
#pragma unroll
                    for (int nt = 0; nt < 2; nt++)
                        accG[mt][nt] = mfma32(a[mt][kf], bq[nt], accG[mt][nt]);
            }
            __builtin_amdgcn_s_setprio(0);
            if (g == 3) {
                // ---- merge: acc2 = acc2*r + u*accG ----
#pragma unroll
                for (int mt = 0; mt < 2; mt++)
#pragma unroll
                    for (int r = 0; r < 16; r++) {
                        int rowl = (mw << 6) + (mt << 5) + (r & 3) + ((r >> 2) << 3) + (hi << 2);
                        float rr = rs_[rowl];
                        float uu = us_[rowl];
#pragma unroll
                        for (int nt = 0; nt < 2; nt++)
                            acc2[mt][nt][r] = acc2[mt][nt][r] * rr + uu * accG[mt][nt][r];
                    }
            }
            asm volatile("s_waitcnt lgkmcnt(0)" ::: "memory");
            __builtin_amdgcn_s_barrier();
        }
    }
    // ---- epilogue: normalize by partition function, mask ----
    if (tid < 128) {
        float s = 0.f;
#pragma unroll
        for (int e2 = 0; e2 < 8; e2++) s += __expf(nbs[tid][e2] - m_run);
        scr[tid] = mreg ? (1.0f / s) : 0.f;
    }
    __syncthreads();
#pragma unroll
    for (int mt = 0; mt < 2; mt++)
#pragma unroll
        for (int r = 0; r < 16; r++) {
            int rowl = (mw << 6) + (mt << 5) + (r & 3) + ((r >> 2) << 3) + (hi << 2);
            float si = scr[rowl];
            float* orow = out + (size_t)(row0 + rowl) * C_;
#pragma unroll
            for (int nt = 0; nt < 2; nt++)
                __builtin_nontemporal_store(acc2[mt][nt][r] * si, orow + nwo + (nt << 5) + c_);
        }
}

// ---------------- launch ----------------

extern "C" void kernel_launch(void* const* d_in, const int* in_sizes, int n_in,
                              void* d_out, int out_size, void* d_ws, size_t ws_size,
                              hipStream_t stream) {
    (void)in_sizes; (void)n_in; (void)out_size; (void)ws_size;
    const float* x        = (const float*)d_in[0];
    const int*   mask     = (const int*)d_in[1];
    const float* lnw      = (const float*)d_in[2];
    const float* lnb      = (const float*)d_in[3];
    const float* W1       = (const float*)d_in[4];
    const float* b1       = (const float*)d_in[5];
    const float* W2       = (const float*)d_in[6];
    const float* b2       = (const float*)d_in[7];
    const float* We       = (const float*)d_in[8];
    const float* be       = (const float*)d_in[9];
    const float* log_beta = (const float*)d_in[10];
    const float* prior    = (const float*)d_in[11];
    float* out = (float*)d_out;
    char* ws = (char*)d_ws;

    constexpr size_t OFF_XB    = 0;                       // 16 MB
    constexpr size_t OFF_W1T   = 16777216;                // 1 MB
    constexpr size_t OFF_W2T   = 17825792;                // 1 MB
    constexpr size_t OFF_V2    = 18874368;                // 8 KB
    constexpr size_t OFF_C2    = 18882560;                // 32 B
    constexpr size_t OFF_S1    = 18882592;                // 4 KB
    constexpr size_t OFF_S2    = 18886688;                // 4 KB
    constexpr size_t OFF_N     = 18890784;                // 16 B
    constexpr size_t OFF_STATS = 18890800;                // 12 KB
    constexpr size_t OFF_BIAS  = 18903088;                // 32 KB

    unsigned short* xb  = (unsigned short*)(ws + OFF_XB);
    unsigned short* w1t = (unsigned short*)(ws + OFF_W1T);
    unsigned short* w2t = (unsigned short*)(ws + OFF_W2T);
    float* v2    = (float*)(ws + OFF_V2);
    float* c2    = (float*)(ws + OFF_C2);
    float* S1    = (float*)(ws + OFF_S1);
    float* S2    = (float*)(ws + OFF_S2);
    float* ncnt  = (float*)(ws + OFF_N);
    float* stats = (float*)(ws + OFF_STATS);
    float* bias  = (float*)(ws + OFF_BIAS);

    hipMemsetAsync(ws + OFF_S1, 0, 4096 + 4096 + 16, stream);

    k_w1t<<<128, 256, 0, stream>>>(W1, w1t);
    k_w2t<<<128, 256, 0, stream>>>(W2, w2t);
    k_v2<<<2048, 256, 0, stream>>>(W2, We, b2, be, v2, c2);
    k_stats<<<256, 256, 0, stream>>>(x, mask, lnw, lnb, S1, S2, ncnt, xb);
    k_stats_fin<<<4, 256, 0, stream>>>(S1, S2, ncnt, stats);
    k_bias<<<32, 256, 0, stream>>>(W1, b1, stats, bias);
    k_fused<<<256, 512, 0, stream>>>(xb, w1t, w2t, bias, v2, c2, mask, b2, log_beta, prior, out);
}

// Round 7
// 333.380 us; speedup vs baseline: 1.4630x; 1.4630x over previous
//
#include <hip/hip_runtime.h>
#include <cmath>

#define B_ 4
#define T_ 8192
#define C_ 256
#define E_ 8
#define M_ (B_*T_)

typedef __bf16 bf16x8 __attribute__((ext_vector_type(8)));
typedef float  f32x4  __attribute__((ext_vector_type(4)));

typedef const __attribute__((address_space(1))) unsigned int* gas_t;
typedef __attribute__((address_space(3))) unsigned int* las_t;

static __device__ __forceinline__ unsigned short f2bf(float f) {
    union { float fv; unsigned u; } v; v.fv = f;
    unsigned r = v.u + 0x7FFFu + ((v.u >> 16) & 1u);
    return (unsigned short)(r >> 16);
}

// Abramowitz-Stegun 7.1.26: |err| <= 1.5e-7
static __device__ __forceinline__ float fast_erf(float x) {
    float ax = fabsf(x);
    float t = __builtin_amdgcn_rcpf(1.0f + 0.3275911f * ax);
    float p = ((((1.061405429f * t - 1.453152027f) * t) + 1.421413741f) * t - 0.284496736f) * t + 0.254829592f;
    float y = 1.0f - p * t * __expf(-ax * ax);
    return copysignf(y, x);
}

static __device__ __forceinline__ float gelu_f(float x) {
    return 0.5f * x * (1.0f + fast_erf(x * 0.7071067811865476f));
}

static __device__ __forceinline__ f32x4 mfma16(bf16x8 a, bf16x8 b, f32x4 c) {
    return __builtin_amdgcn_mfma_f32_16x16x32_bf16(a, b, c, 0, 0, 0);
}

// stage one 16KB weight chunk [256 cols][32 k] bf16 into LDS, bank-swizzled.
// LDS 16B-slot s holds (col = s>>2, kseg = (s&3)^(col&3)).
// Read side: slot = (col<<2) + (kseg ^ (col&3)) -> a wave's 16-tile B-read
// covers all 64 slots of a 1KB stripe exactly once (conflict-free).
// LDS dest stays linear (global_load_lds constraint); source pre-swizzled.
static __device__ __forceinline__ void stage_swz(const unsigned short* __restrict__ src,
                                                 unsigned short* lds_base, int tid) {
#pragma unroll
    for (int i = 0; i < 4; i++) {
        int s = i * 256 + tid;
        int col = s >> 2;
        int kseg = (s & 3) ^ (col & 3);
        const unsigned short* gp = src + (col << 8) + (kseg << 3);
        unsigned short* lp = lds_base + ((i * 256 + (tid & ~63)) << 3);
        __builtin_amdgcn_global_load_lds((gas_t)(const void*)gp, (las_t)(void*)lp, 16, 0, 0);
    }
}

// ---------------- prep kernels ----------------

// w1t[e][c][k] = W1[e][k][c], k in [0,256)  (tiled coalesced transpose)
__global__ void k_w1t(const float* __restrict__ W1, unsigned short* __restrict__ w1t) {
    __shared__ float tile[64][65];
    int e = blockIdx.x >> 4, kt = (blockIdx.x >> 2) & 3, ct = blockIdx.x & 3;
    int k0 = kt << 6, c0 = ct << 6;
    const float* src = W1 + ((size_t)e << 18) + ((size_t)k0 << 8) + c0;
    int r = threadIdx.x >> 6, col = threadIdx.x & 63;
#pragma unroll
    for (int i = 0; i < 16; i++)
        tile[r + i * 4][col] = src[(size_t)(r + i * 4) * 256 + col];
    __syncthreads();
    unsigned short* dst = w1t + (e << 16) + (c0 << 8) + k0;
#pragma unroll
    for (int i = 0; i < 16; i++)
        dst[(r + i * 4) * 256 + col] = f2bf(tile[col][r + i * 4]);
}

// w2t[e][f][c] = W2[e][c][f]
__global__ void k_w2t(const float* __restrict__ W2, unsigned short* __restrict__ w2t) {
    __shared__ float tile[64][65];
    int e = blockIdx.x >> 4, ct = (blockIdx.x >> 2) & 3, ft = blockIdx.x & 3;
    int c0 = ct << 6, f0 = ft << 6;
    const float* src = W2 + ((size_t)e << 16) + ((size_t)c0 << 8) + f0;
    int r = threadIdx.x >> 6, col = threadIdx.x & 63;
#pragma unroll
    for (int i = 0; i < 16; i++)
        tile[r + i * 4][col] = src[(size_t)(r + i * 4) * 256 + col];
    __syncthreads();
    unsigned short* dst = w2t + (e << 16) + (f0 << 8) + c0;
#pragma unroll
    for (int i = 0; i < 16; i++)
        dst[(r + i * 4) * 256 + col] = f2bf(tile[col][r + i * 4]);
}

// v2[e][c] = sum_f W2[e,c,f]*We[e,f];
// bc2[e] = -beta*( sum_f b2[e,f]*We[e,f] + be[e] + prior[e] );  bbeta[0] = beta
__global__ void k_v2(const float* __restrict__ W2, const float* __restrict__ We,
                     const float* __restrict__ b2, const float* __restrict__ be,
                     const float* __restrict__ log_beta, const float* __restrict__ prior,
                     float* __restrict__ v2, float* __restrict__ bc2, float* __restrict__ bbeta) {
    __shared__ float sm[4];
    int e = blockIdx.x >> 8, c = blockIdx.x & 255, f = threadIdx.x;
    float wef = We[(e << 8) + f];
    float v = W2[((((e << 8) + c) << 8)) + f] * wef;
#pragma unroll
    for (int m = 32; m >= 1; m >>= 1) v += __shfl_xor(v, m);
    if ((f & 63) == 0) sm[f >> 6] = v;
    __syncthreads();
    if (f == 0) v2[(e << 8) + c] = sm[0] + sm[1] + sm[2] + sm[3];
    if (c == 0) {
        __syncthreads();
        float u = b2[(e << 8) + f] * wef;
#pragma unroll
        for (int m = 32; m >= 1; m >>= 1) u += __shfl_xor(u, m);
        if ((f & 63) == 0) sm[f >> 6] = u;
        __syncthreads();
        if (f == 0) {
            float beta = __expf(log_beta[0]);
            float c2e = sm[0] + sm[1] + sm[2] + sm[3] + be[e];
            bc2[e] = -beta * (c2e + prior[e]);
            if (e == 0) bbeta[0] = beta;
        }
    }
}

// ---------------- LN + masked stats (+ x -> bf16 conversion fused) ----------------

__global__ void k_stats(const float* __restrict__ x, const int* __restrict__ mask,
                        const float* __restrict__ lnw, const float* __restrict__ lnb,
                        float* __restrict__ S1, float* __restrict__ S2, float* __restrict__ ncnt,
                        unsigned short* __restrict__ xb) {
    int b = blockIdx.x >> 6;
    int chunk = blockIdx.x & 63;
    int wid = threadIdx.x >> 6, lane = threadIdx.x & 63;
    int c0 = lane << 2;
    float4 w4 = *reinterpret_cast<const float4*>(lnw + c0);
    float4 b4 = *reinterpret_cast<const float4*>(lnb + c0);
    float a1[4] = {0,0,0,0}, a2[4] = {0,0,0,0};
    int cnt = 0;
    int tbase = chunk * 128;
    for (int r = wid; r < 128; r += 4) {
        int row = b * T_ + tbase + r;
        float4 xv = *reinterpret_cast<const float4*>(x + (size_t)row * C_ + c0);
        ushort4 o;
        o.x = f2bf(xv.x); o.y = f2bf(xv.y); o.z = f2bf(xv.z); o.w = f2bf(xv.w);
        *reinterpret_cast<ushort4*>(xb + (size_t)row * C_ + c0) = o;
        float s1 = xv.x + xv.y + xv.z + xv.w;
        float s2 = xv.x*xv.x + xv.y*xv.y + xv.z*xv.z + xv.w*xv.w;
#pragma unroll
        for (int m = 1; m < 64; m <<= 1) { s1 += __shfl_xor(s1, m); s2 += __shfl_xor(s2, m); }
        if (mask[row]) {
            float mu = s1 * (1.f / C_);
            float var = s2 * (1.f / C_) - mu * mu;
            float rs = rsqrtf(var + 1e-5f);
            float hv;
            hv = (xv.x - mu) * rs * w4.x + b4.x; a1[0] += hv; a2[0] += hv * hv;
            hv = (xv.y - mu) * rs * w4.y + b4.y; a1[1] += hv; a2[1] += hv * hv;
            hv = (xv.z - mu) * rs * w4.z + b4.z; a1[2] += hv; a2[2] += hv * hv;
            hv = (xv.w - mu) * rs * w4.w + b4.w; a1[3] += hv; a2[3] += hv * hv;
            cnt++;
        }
    }
    __shared__ float red[4][256];
    __shared__ int rc[4];
#pragma unroll
    for (int j = 0; j < 4; j++) red[wid][c0 + j] = a1[j];
    if (lane == 0) rc[wid] = cnt;
    __syncthreads();
    int ch = threadIdx.x;
    float s = red[0][ch] + red[1][ch] + red[2][ch] + red[3][ch];
    atomicAdd(&S1[(b << 8) + ch], s);
    if (threadIdx.x == 0) atomicAdd(&ncnt[b], (float)(rc[0] + rc[1] + rc[2] + rc[3]));
    __syncthreads();
#pragma unroll
    for (int j = 0; j < 4; j++) red[wid][c0 + j] = a2[j];
    __syncthreads();
    s = red[0][ch] + red[1][ch] + red[2][ch] + red[3][ch];
    atomicAdd(&S2[(b << 8) + ch], s);
}

__global__ void k_stats_fin(const float* __restrict__ S1, const float* __restrict__ S2,
                            const float* __restrict__ ncnt, float* __restrict__ stats) {
    int b = blockIdx.x, c = threadIdx.x;
    float n = fmaxf(ncnt[b], 1.f);
    float mean = S1[(b << 8) + c] / n;
    float var_b = fmaxf(S2[(b << 8) + c] / n - mean * mean, 0.f);
    float var_u = (n > 1.f) ? (var_b * (n / fmaxf(n - 1.f, 1e-9f))) : var_b;
    float std_u = fmaxf(sqrtf(var_u), 1e-9f);
    stats[b * 768 + 0 * 256 + c] = mean;
    stats[b * 768 + 1 * 256 + c] = std_u;
    stats[b * 768 + 2 * 256 + c] = var_u;
}

__global__ void k_bias(const float* __restrict__ W1, const float* __restrict__ b1,
                       const float* __restrict__ stats, float* __restrict__ bias) {
    int b = blockIdx.x >> 3, e = blockIdx.x & 7, c = threadIdx.x;
    __shared__ float sm[768];
    for (int i = threadIdx.x; i < 768; i += 256) sm[i] = stats[b * 768 + i];
    __syncthreads();
    const float* w = W1 + (size_t)e * 1024 * 256;
    float acc = b1[(e << 8) + c];
#pragma unroll 4
    for (int j = 0; j < 256; j++) {
        acc += sm[j]       * w[(256 + j) * 256 + c];
        acc += sm[256 + j] * w[(512 + j) * 256 + c];
        acc += sm[512 + j] * w[(768 + j) * 256 + c];
    }
    bias[((b << 3) + e) * 256 + c] = acc;
}

// ---------------- fused: GEMM1 + gelu + energy + online softmax + GEMM2 ----------------
// Round-2 k_out skeleton (proven: 1.56us/phase, FETCH 28MB): 512 blocks x 256 thr,
// 64 rows/block, 4 waves x (16 rows, 256 cols), 16x16x32 MFMA, 16KB chunks,
// __syncthreads double-buffer. Added: per-lane online softmax over E (kills
// k_energy) and conflict-free staging swizzle (kills the 17.4M B-read conflicts).

__global__ __launch_bounds__(256, 2) void k_fused(
    const unsigned short* __restrict__ xb, const unsigned short* __restrict__ w1t,
    const unsigned short* __restrict__ w2t, const float* __restrict__ bias,
    const float* __restrict__ v2, const float* __restrict__ bc2,
    const float* __restrict__ bbeta, const int* __restrict__ mask,
    const float* __restrict__ b2, float* __restrict__ out) {
    __shared__ unsigned short bstage[2][8192];  // 2 x 16KB swizzled weight chunks
    __shared__ unsigned short h1_s[4][4096];    // per-wave [16][256] bf16, row-XOR
    __shared__ float b2s[2048];                 // [8][256]

    int row0 = blockIdx.x << 6;
    int b = row0 >> 13;
    int tid = threadIdx.x;
    int wid = tid >> 6, lane = tid & 63;
    int rlo = lane & 15, khi = lane >> 4;
    unsigned short* h1w = h1_s[wid];

    for (int i = tid; i < 2048; i += 256) b2s[i] = b2[i];

    // per-lane constants
    float beta = bbeta[0];
    float bc2r[8];
#pragma unroll
    for (int e = 0; e < 8; e++) bc2r[e] = bc2[e];
    int mask4[4];
#pragma unroll
    for (int i = 0; i < 4; i++) mask4[i] = mask[row0 + (wid << 4) + (khi << 2) + i];

    // A rows in registers (16 rows/wave), reused across all experts
    const unsigned short* arow = xb + (size_t)(row0 + (wid << 4) + rlo) * C_ + (khi << 3);
    bf16x8 areg[8];
#pragma unroll
    for (int kk = 0; kk < 8; kk++) areg[kk] = *reinterpret_cast<const bf16x8*>(arow + (kk << 5));

    f32x4 acc2[16];
#pragma unroll
    for (int n = 0; n < 16; n++)
#pragma unroll
        for (int i = 0; i < 4; i++) acc2[n][i] = 0.f;
    float m_run[4], s_run[4];
#pragma unroll
    for (int i = 0; i < 4; i++) { m_run[i] = -3.0e38f; s_run[i] = 0.f; }

    stage_swz(w1t, &bstage[0][0], tid);
    __syncthreads();

    int pc = 0;
    for (int e = 0; e < E_; e++) {
        // ---- GEMM1: acc1 = x @ W1x + bias_fold (8 staged phases) ----
        const float* bre = bias + (((b << 3) + e) << 8);
        f32x4 acc1[16];
#pragma unroll
        for (int n = 0; n < 16; n++) {
            float bv = bre[(n << 4) + rlo];
#pragma unroll
            for (int i = 0; i < 4; i++) acc1[n][i] = bv;
        }
#pragma unroll
        for (int kk = 0; kk < 8; kk++) {
            int nc = pc + 1;
            if (nc < 128) {
                const unsigned short* nsrc = (((nc >> 3) & 1) ? w2t : w1t) + ((nc >> 4) << 16) + ((nc & 7) << 5);
                stage_swz(nsrc, &bstage[nc & 1][0], tid);
            }
            const unsigned short* bs = &bstage[pc & 1][0];
            bf16x8 a = areg[kk];
#pragma unroll
            for (int n = 0; n < 16; n++) {
                int col = (n << 4) + rlo;
                int slot = (col << 2) + (khi ^ (col & 3));
                bf16x8 bf = *reinterpret_cast<const bf16x8*>(bs + (slot << 3));
                acc1[n] = mfma16(a, bf, acc1[n]);
            }
            __syncthreads();
            pc++;
        }
        // ---- gelu (in place) + energy row-reduce + online softmax (pure regs) ----
        float v2v[16];
#pragma unroll
        for (int n = 0; n < 16; n++) v2v[n] = v2[(e << 8) + (n << 4) + rlo];
        float epr[4] = {0,0,0,0};
#pragma unroll
        for (int n = 0; n < 16; n++)
#pragma unroll
            for (int i = 0; i < 4; i++) {
                float g = gelu_f(acc1[n][i]);
                acc1[n][i] = g;
                epr[i] += g * v2v[n];
            }
#pragma unroll
        for (int m = 1; m < 16; m <<= 1)
#pragma unroll
            for (int i = 0; i < 4; i++) epr[i] += __shfl_xor(epr[i], m);
        float rr[4], uu[4];
#pragma unroll
        for (int i = 0; i < 4; i++) {
            float nb = -beta * epr[i] + bc2r[e];     // all 16 lanes of row group agree
            float mn = fmaxf(m_run[i], nb);
            rr[i] = __expf(m_run[i] - mn);
            uu[i] = __expf(nb - mn);
            s_run[i] = s_run[i] * rr[i] + uu[i];
            m_run[i] = mn;
        }
        // ---- unscaled gelu(h1) -> per-wave LDS slice (row-XOR swizzle) ----
#pragma unroll
        for (int n = 0; n < 16; n++) {
#pragma unroll
            for (int i = 0; i < 4; i++) {
                int row_l = (khi << 2) + i;
                int col = (n << 4) + rlo;
                int byteoff = ((row_l << 9) + (col << 1)) ^ ((row_l & 7) << 4);
                *reinterpret_cast<unsigned short*>(reinterpret_cast<char*>(h1w) + byteoff)
                    = f2bf(acc1[n][i]);
            }
        }
        // ---- GEMM2: acc1 = gelu_h1 @ W2 + b2 (8 staged phases) ----
#pragma unroll
        for (int n = 0; n < 16; n++) {
            float bv = b2s[(e << 8) + (n << 4) + rlo];
#pragma unroll
            for (int i = 0; i < 4; i++) acc1[n][i] = bv;
        }
#pragma unroll
        for (int kk = 0; kk < 8; kk++) {
            int nc = pc + 1;
            if (nc < 128) {
                const unsigned short* nsrc = (((nc >> 3) & 1) ? w2t : w1t) + ((nc >> 4) << 16) + ((nc & 7) << 5);
                stage_swz(nsrc, &bstage[nc & 1][0], tid);
            }
            const unsigned short* bs = &bstage[pc & 1][0];
            int byteoff = ((rlo << 9) + (kk << 6) + (khi << 4)) ^ ((rlo & 7) << 4);
            bf16x8 a2 = *reinterpret_cast<const bf16x8*>(reinterpret_cast<char*>(h1w) + byteoff);
#pragma unroll
            for (int n = 0; n < 16; n++) {
                int col = (n << 4) + rlo;
                int slot = (col << 2) + (khi ^ (col & 3));
                bf16x8 bf = *reinterpret_cast<const bf16x8*>(bs + (slot << 3));
                acc1[n] = mfma16(a2, bf, acc1[n]);
            }
            __syncthreads();
            pc++;
        }
        // ---- merge: acc2 = acc2*rr + uu*acc1 ----
#pragma unroll
        for (int n = 0; n < 16; n++)
#pragma unroll
            for (int i = 0; i < 4; i++)
                acc2[n][i] = acc2[n][i] * rr[i] + uu[i] * acc1[n][i];
    }
    // ---- epilogue: divide by partition sum, mask ----
    float si[4];
#pragma unroll
    for (int i = 0; i < 4; i++) si[i] = mask4[i] ? (1.0f / s_run[i]) : 0.f;
#pragma unroll
    for (int n = 0; n < 16; n++) {
        int col = (n << 4) + rlo;
#pragma unroll
        for (int i = 0; i < 4; i++)
            out[(size_t)(row0 + (wid << 4) + (khi << 2) + i) * C_ + col] = acc2[n][i] * si[i];
    }
}

// ---------------- launch ----------------

extern "C" void kernel_launch(void* const* d_in, const int* in_sizes, int n_in,
                              void* d_out, int out_size, void* d_ws, size_t ws_size,
                              hipStream_t stream) {
    (void)in_sizes; (void)n_in; (void)out_size; (void)ws_size;
    const float* x        = (const float*)d_in[0];
    const int*   mask     = (const int*)d_in[1];
    const float* lnw      = (const float*)d_in[2];
    const float* lnb      = (const float*)d_in[3];
    const float* W1       = (const float*)d_in[4];
    const float* b1       = (const float*)d_in[5];
    const float* W2       = (const float*)d_in[6];
    const float* b2       = (const float*)d_in[7];
    const float* We       = (const float*)d_in[8];
    const float* be       = (const float*)d_in[9];
    const float* log_beta = (const float*)d_in[10];
    const float* prior    = (const float*)d_in[11];
    float* out = (float*)d_out;
    char* ws = (char*)d_ws;

    constexpr size_t OFF_XB    = 0;                       // 16 MB
    constexpr size_t OFF_W1T   = 16777216;                // 1 MB
    constexpr size_t OFF_W2T   = 17825792;                // 1 MB
    constexpr size_t OFF_V2    = 18874368;                // 8 KB
    constexpr size_t OFF_BC2   = 18882560;                // 32 B
    constexpr size_t OFF_S1    = 18882592;                // 4 KB
    constexpr size_t OFF_S2    = 18886688;                // 4 KB
    constexpr size_t OFF_N     = 18890784;                // 16 B
    constexpr size_t OFF_STATS = 18890800;                // 12 KB
    constexpr size_t OFF_BIAS  = 18903088;                // 32 KB
    constexpr size_t OFF_BB    = 18935856;                // 4 B

    unsigned short* xb  = (unsigned short*)(ws + OFF_XB);
    unsigned short* w1t = (unsigned short*)(ws + OFF_W1T);
    unsigned short* w2t = (unsigned short*)(ws + OFF_W2T);
    float* v2    = (float*)(ws + OFF_V2);
    float* bc2   = (float*)(ws + OFF_BC2);
    float* S1    = (float*)(ws + OFF_S1);
    float* S2    = (float*)(ws + OFF_S2);
    float* ncnt  = (float*)(ws + OFF_N);
    float* stats = (float*)(ws + OFF_STATS);
    float* bias  = (float*)(ws + OFF_BIAS);
    float* bbeta = (float*)(ws + OFF_BB);

    hipMemsetAsync(ws + OFF_S1, 0, 4096 + 4096 + 16, stream);

    k_w1t<<<128, 256, 0, stream>>>(W1, w1t);
    k_w2t<<<128, 256, 0, stream>>>(W2, w2t);
    k_v2<<<2048, 256, 0, stream>>>(W2, We, b2, be, log_beta, prior, v2, bc2, bbeta);
    k_stats<<<256, 256, 0, stream>>>(x, mask, lnw, lnb, S1, S2, ncnt, xb);
    k_stats_fin<<<4, 256, 0, stream>>>(S1, S2, ncnt, stats);
    k_bias<<<32, 256, 0, stream>>>(W1, b1, stats, bias);
    k_fused<<<512, 256, 0, stream>>>(xb, w1t, w2t, bias, v2, bc2, bbeta, mask, b2, out);
}